// Round 1
// baseline (4834.492 us; speedup 1.0000x reference)
//
#include <hip/hip_runtime.h>
#include <math.h>

#define MUL    16
#define CIN    64
#define COUT   144
#define SDIM   40
#define SP     (SDIM*SDIM*SDIM)      // 64000
#define NTAP   125
#define KW_ELEMS (NTAP*CIN*COUT)     // 1,152,000 floats = 4.608 MB

// ---------------- constants ----------------
#define SQ3    1.7320508075688772
#define SQ5    2.23606797749979
#define PW0    0.17677669529663687   // sqrt(1/32)
#define PW1    0.25                  // sqrt(3/48)
#define PW2    0.3952847075210474    // sqrt(5/32)
#define PW0_D3 0.10206207261596575   // PW0/sqrt3
#define PW1_D3 0.14433756729740643   // PW1/sqrt3
#define PW2_D5 0.17677669529663687   // PW2/sqrt5
#define C_S    0.3651483716701107    // sqrt(2/15)
#define C_H    0.31622776601683794   // 0.5*sqrt(3)*s

// C112[i][j][k]
__device__ __constant__ double dC112[3][3][5] = {
  { {0.0, 0.0, -0.5*C_S, 0.0, -C_H},
    {0.0, C_H, 0.0,      0.0, 0.0 },
    {C_H, 0.0, 0.0,      0.0, 0.0 } },
  { {0.0, C_H, 0.0, 0.0, 0.0},
    {0.0, 0.0, C_S, 0.0, 0.0},
    {0.0, 0.0, 0.0, C_H, 0.0} },
  { {C_H, 0.0, 0.0, 0.0, 0.0},
    {0.0, 0.0, 0.0, C_H, 0.0},
    {0.0, 0.0, -0.5*C_S, 0.0, C_H} }
};

// ---------------- kernel-weight builder ----------------
// kw[((kx*5+ky)*5+kz)*CIN*COUT + i*COUT + o]
__global__ void build_kw(const float* __restrict__ w_tp, float* __restrict__ kw) {
  int gid = blockIdx.x * 256 + threadIdx.x;
  if (gid >= KW_ELEMS) return;
  int o   = gid % COUT;
  int i   = (gid / COUT) % CIN;
  int tap = gid / (COUT * CIN);
  int kz = tap % 5, ky = (tap / 5) % 5, kx = tap / 25;

  double lx = -1.0 + 0.5 * kx, ly = -1.0 + 0.5 * ky, lz = -1.0 + 0.5 * kz;
  double d = sqrt(lx*lx + ly*ly + lz*lz);

  double emb[5];
  #pragma unroll
  for (int t = 0; t < 5; ++t) {
    double diff = (d - (t + 1) / 6.0) * 6.0;
    double a = diff + 1.0, bb = 1.0 - diff;
    double sa = (a  > 0.0) ? exp(-1.0 / a)  : 0.0;
    double sb = (bb > 0.0) ? exp(-1.0 / bb) : 0.0;
    emb[t] = 1.14136 * exp(2.0) * sa * sb;
  }
  double inv = 1.0 / fmax(d, 1e-12);
  double ux = lx * inv, uy = ly * inv, uz = lz * inv;
  double sh1[3] = { SQ3 * ux, SQ3 * uy, SQ3 * uz };
  double sh2[5] = { SQ5 * SQ3 * ux * uz,
                    SQ5 * SQ3 * ux * uy,
                    SQ5 * (uy*uy - 0.5*(ux*ux + uz*uz)),
                    SQ5 * SQ3 * uy * uz,
                    SQ5 * 0.5 * SQ3 * (uz*uz - ux*ux) };

  // W(n,u,w) = (1/5^1.5) * sum_t emb[t] * w_tp[t*1792 + n*256 + u*16 + w]
  #define WVAL(n, u, w) ({                                              \
      int base_ = (n)*256 + (u)*16 + (w);                               \
      double a_ = 0.0;                                                  \
      _Pragma("unroll")                                                 \
      for (int t_ = 0; t_ < 5; ++t_)                                    \
        a_ += emb[t_] * (double)w_tp[t_*1792 + base_];                  \
      (a_ * 0.08944271909999159); })

  double val;
  if (i < MUL) {
    int u = i;
    if (o < MUL) {
      val = PW0 * WVAL(0, u, o);
    } else if (o < 4 * MUL) {
      int w = (o - 16) / 3, k = (o - 16) % 3;
      val = PW1_D3 * sh1[k] * WVAL(1, u, w);
    } else {
      int w = (o - 64) / 5, k = (o - 64) % 5;
      val = PW2_D5 * sh2[k] * WVAL(2, u, w);
    }
  } else {
    int u = (i - 16) / 3, ii = (i - 16) % 3;
    if (o < MUL) {
      val = PW0_D3 * sh1[ii] * WVAL(4, u, o);
    } else if (o < 4 * MUL) {
      int w = (o - 16) / 3, k = (o - 16) % 3;
      double v = 0.0;
      if (ii == k) v += PW1_D3 * WVAL(3, u, w);
      double cs = 0.0;
      #pragma unroll
      for (int j = 0; j < 5; ++j) cs += dC112[ii][k][j] * sh2[j];  // C121[ii,j,k]=C112[ii,k,j]
      v += PW1 * cs * WVAL(6, u, w);
      val = v;
    } else {
      int w = (o - 64) / 5, k = (o - 64) % 5;
      double cs = 0.0;
      #pragma unroll
      for (int j = 0; j < 3; ++j) cs += dC112[ii][j][k] * sh1[j];
      val = PW2 * cs * WVAL(5, u, w);
    }
  }
  kw[gid] = (float)val;
}

// ---------------- self-connection (writes ALL 144 channels) ----------------
__global__ void sc_kernel(const float* __restrict__ x,
                          const float* __restrict__ w0,
                          const float* __restrict__ w1,
                          float* __restrict__ out) {
  int gid = blockIdx.x * 256 + threadIdx.x;
  if (gid >= 2 * SP) return;
  int b = gid / SP, p = gid % SP;
  const float* xb = x + (size_t)b * CIN * SP + p;
  float xv[64];
  #pragma unroll
  for (int c = 0; c < 64; ++c) xv[c] = xb[(size_t)c * SP];
  float* ob = out + (size_t)b * COUT * SP + p;
  #pragma unroll
  for (int w = 0; w < 16; ++w) {
    float s = 0.f;
    #pragma unroll
    for (int u = 0; u < 16; ++u) s = fmaf(w0[u * 16 + w], xv[u], s);
    ob[(size_t)w * SP] = 0.25f * s;
  }
  #pragma unroll
  for (int w = 0; w < 16; ++w) {
    #pragma unroll
    for (int i2 = 0; i2 < 3; ++i2) {
      float s = 0.f;
      #pragma unroll
      for (int u = 0; u < 16; ++u) s = fmaf(w1[u * 16 + w], xv[16 + u * 3 + i2], s);
      ob[(size_t)(16 + w * 3 + i2) * SP] = 0.25f * s;
    }
  }
  #pragma unroll
  for (int o = 64; o < 144; ++o) ob[(size_t)o * SP] = 0.f;
}

// ---------------- direct conv, register-tiled ----------------
// block: 256 threads = 16 o-threads (9 o each) x 16 p-threads (10 p each)
// tile: 144 out-ch x (4 y x 40 z) positions; grid = b(2) * X(40) * Ytile(10)
#define IC 8
__global__ __launch_bounds__(256, 2)
void conv_kernel(const float* __restrict__ x,
                 const float* __restrict__ kw,
                 float* __restrict__ out) {
  __shared__ float x_lds[IC][8][44];
  __shared__ float k_lds[5][IC][COUT];

  int tid = threadIdx.x;
  int bid = blockIdx.x;
  int tileY = bid % 10;
  int X     = (bid / 10) % SDIM;
  int b     = bid / 400;
  int Y0 = tileY * 4;

  int p_thr = tid & 15, o_thr = tid >> 4;
  int y_loc = p_thr >> 2;          // 0..3
  int z0    = (p_thr & 3) * 10;    // 0/10/20/30
  int o_base = o_thr * 9;

  float acc[9][10];
  #pragma unroll
  for (int a = 0; a < 9; ++a)
    #pragma unroll
    for (int jj = 0; jj < 10; ++jj) acc[a][jj] = 0.f;

  const float* xb = x + (size_t)b * CIN * SP;

  #pragma unroll 1
  for (int ic = 0; ic < CIN / IC; ++ic) {
    #pragma unroll 1
    for (int dx = 0; dx < 5; ++dx) {
      int xs = X + dx - 2;
      if (xs < 0 || xs >= SDIM) continue;   // uniform across block
      __syncthreads();                       // protect x_lds from prior readers
      for (int idx = tid; idx < IC * 8 * 44; idx += 256) {
        int i   = idx / (8 * 44);
        int rem = idx % (8 * 44);
        int yy  = rem / 44, zz = rem % 44;
        int gy = Y0 + yy - 2, gz = zz - 2;
        float v = 0.f;
        if (gy >= 0 && gy < SDIM && gz >= 0 && gz < SDIM)
          v = xb[((size_t)(ic * IC + i) * SDIM + xs) * 1600 + gy * SDIM + gz];
        x_lds[i][yy][zz] = v;
      }
      #pragma unroll 1
      for (int dy = 0; dy < 5; ++dy) {
        __syncthreads();                     // protect k_lds; also covers x_lds stage
        for (int idx = tid; idx < 5 * IC * COUT; idx += 256) {
          int dz  = idx / (IC * COUT);
          int rem = idx % (IC * COUT);
          int i = rem / COUT, o = rem % COUT;
          k_lds[dz][i][o] =
            kw[((size_t)((dx * 5 + dy) * 5 + dz) * CIN + ic * IC + i) * COUT + o];
        }
        __syncthreads();
        #pragma unroll 1
        for (int i = 0; i < IC; ++i) {
          float xr[14];
          #pragma unroll
          for (int t = 0; t < 14; ++t) xr[t] = x_lds[i][y_loc + dy][z0 + t];
          #pragma unroll
          for (int dz = 0; dz < 5; ++dz) {
            float kv[9];
            #pragma unroll
            for (int oo = 0; oo < 9; ++oo) kv[oo] = k_lds[dz][i][o_base + oo];
            #pragma unroll
            for (int oo = 0; oo < 9; ++oo)
              #pragma unroll
              for (int j = 0; j < 10; ++j)
                acc[oo][j] = fmaf(kv[oo], xr[dz + j], acc[oo][j]);
          }
        }
      }
    }
  }

  float* ob = out + (size_t)b * COUT * SP + (size_t)X * 1600;
  #pragma unroll
  for (int oo = 0; oo < 9; ++oo) {
    int o = o_base + oo;
    #pragma unroll
    for (int j = 0; j < 10; ++j) {
      size_t idx = (size_t)o * SP + (size_t)(Y0 + y_loc) * SDIM + z0 + j;
      ob[idx] += 0.1f * acc[oo][j];
    }
  }
}

// ---------------- launcher ----------------
extern "C" void kernel_launch(void* const* d_in, const int* in_sizes, int n_in,
                              void* d_out, int out_size, void* d_ws, size_t ws_size,
                              hipStream_t stream) {
  const float* x     = (const float*)d_in[0];
  const float* w_sc0 = (const float*)d_in[1];
  const float* w_sc1 = (const float*)d_in[2];
  const float* w_tp  = (const float*)d_in[3];
  float* out = (float*)d_out;
  float* kw  = (float*)d_ws;   // 4.608 MB

  build_kw<<<(KW_ELEMS + 255) / 256, 256, 0, stream>>>(w_tp, kw);
  sc_kernel<<<(2 * SP + 255) / 256, 256, 0, stream>>>(x, w_sc0, w_sc1, out);
  conv_kernel<<<2 * SDIM * 10, 256, 0, stream>>>(x, kw, out);
}

// Round 2
// 4493.328 us; speedup vs baseline: 1.0759x; 1.0759x over previous
//
#include <hip/hip_runtime.h>
#include <math.h>

#define MUL    16
#define CIN    64
#define COUT   144
#define SDIM   40
#define SP     (SDIM*SDIM*SDIM)      // 64000
#define NTAP   125
#define KW_ELEMS (NTAP*CIN*COUT)     // 1,152,000 floats = 4.608 MB

// ---------------- constants ----------------
#define SQ3    1.7320508075688772
#define SQ5    2.23606797749979
#define PW0    0.17677669529663687   // sqrt(1/32)
#define PW1    0.25                  // sqrt(3/48)
#define PW2    0.3952847075210474    // sqrt(5/32)
#define PW0_D3 0.10206207261596575   // PW0/sqrt3
#define PW1_D3 0.14433756729740643   // PW1/sqrt3
#define PW2_D5 0.17677669529663687   // PW2/sqrt5
#define C_S    0.3651483716701107    // sqrt(2/15)
#define C_H    0.31622776601683794   // 0.5*sqrt(3)*s

// C112[i][j][k]
__device__ __constant__ double dC112[3][3][5] = {
  { {0.0, 0.0, -0.5*C_S, 0.0, -C_H},
    {0.0, C_H, 0.0,      0.0, 0.0 },
    {C_H, 0.0, 0.0,      0.0, 0.0 } },
  { {0.0, C_H, 0.0, 0.0, 0.0},
    {0.0, 0.0, C_S, 0.0, 0.0},
    {0.0, 0.0, 0.0, C_H, 0.0} },
  { {C_H, 0.0, 0.0, 0.0, 0.0},
    {0.0, 0.0, 0.0, C_H, 0.0},
    {0.0, 0.0, -0.5*C_S, 0.0, C_H} }
};

// ---------------- kernel-weight builder ----------------
// kw[tap*CIN*COUT + i*COUT + o],  tap = (kx*5+ky)*5+kz
__global__ void build_kw(const float* __restrict__ w_tp, float* __restrict__ kw) {
  int gid = blockIdx.x * 256 + threadIdx.x;
  if (gid >= KW_ELEMS) return;
  int o   = gid % COUT;
  int i   = (gid / COUT) % CIN;
  int tap = gid / (COUT * CIN);
  int kz = tap % 5, ky = (tap / 5) % 5, kx = tap / 25;

  double lx = -1.0 + 0.5 * kx, ly = -1.0 + 0.5 * ky, lz = -1.0 + 0.5 * kz;
  double d = sqrt(lx*lx + ly*ly + lz*lz);

  double emb[5];
  #pragma unroll
  for (int t = 0; t < 5; ++t) {
    double diff = (d - (t + 1) / 6.0) * 6.0;
    double a = diff + 1.0, bb = 1.0 - diff;
    double sa = (a  > 0.0) ? exp(-1.0 / a)  : 0.0;
    double sb = (bb > 0.0) ? exp(-1.0 / bb) : 0.0;
    emb[t] = 1.14136 * exp(2.0) * sa * sb;
  }
  double inv = 1.0 / fmax(d, 1e-12);
  double ux = lx * inv, uy = ly * inv, uz = lz * inv;
  double sh1[3] = { SQ3 * ux, SQ3 * uy, SQ3 * uz };
  double sh2[5] = { SQ5 * SQ3 * ux * uz,
                    SQ5 * SQ3 * ux * uy,
                    SQ5 * (uy*uy - 0.5*(ux*ux + uz*uz)),
                    SQ5 * SQ3 * uy * uz,
                    SQ5 * 0.5 * SQ3 * (uz*uz - ux*ux) };

  #define WVAL(n, u, w) ({                                              \
      int base_ = (n)*256 + (u)*16 + (w);                               \
      double a_ = 0.0;                                                  \
      _Pragma("unroll")                                                 \
      for (int t_ = 0; t_ < 5; ++t_)                                    \
        a_ += emb[t_] * (double)w_tp[t_*1792 + base_];                  \
      (a_ * 0.08944271909999159); })

  double val;
  if (i < MUL) {
    int u = i;
    if (o < MUL) {
      val = PW0 * WVAL(0, u, o);
    } else if (o < 4 * MUL) {
      int w = (o - 16) / 3, k = (o - 16) % 3;
      val = PW1_D3 * sh1[k] * WVAL(1, u, w);
    } else {
      int w = (o - 64) / 5, k = (o - 64) % 5;
      val = PW2_D5 * sh2[k] * WVAL(2, u, w);
    }
  } else {
    int u = (i - 16) / 3, ii = (i - 16) % 3;
    if (o < MUL) {
      val = PW0_D3 * sh1[ii] * WVAL(4, u, o);
    } else if (o < 4 * MUL) {
      int w = (o - 16) / 3, k = (o - 16) % 3;
      double v = 0.0;
      if (ii == k) v += PW1_D3 * WVAL(3, u, w);
      double cs = 0.0;
      #pragma unroll
      for (int j = 0; j < 5; ++j) cs += dC112[ii][k][j] * sh2[j];  // C121[ii,j,k]=C112[ii,k,j]
      v += PW1 * cs * WVAL(6, u, w);
      val = v;
    } else {
      int w = (o - 64) / 5, k = (o - 64) % 5;
      double cs = 0.0;
      #pragma unroll
      for (int j = 0; j < 3; ++j) cs += dC112[ii][j][k] * sh1[j];
      val = PW2 * cs * WVAL(5, u, w);
    }
  }
  kw[gid] = (float)val;
}

// ---------------- self-connection (writes ALL 144 channels) ----------------
__global__ void sc_kernel(const float* __restrict__ x,
                          const float* __restrict__ w0,
                          const float* __restrict__ w1,
                          float* __restrict__ out) {
  int gid = blockIdx.x * 256 + threadIdx.x;
  if (gid >= 2 * SP) return;
  int b = gid / SP, p = gid % SP;
  const float* xb = x + (size_t)b * CIN * SP + p;
  float xv[64];
  #pragma unroll
  for (int c = 0; c < 64; ++c) xv[c] = xb[(size_t)c * SP];
  float* ob = out + (size_t)b * COUT * SP + p;
  #pragma unroll
  for (int w = 0; w < 16; ++w) {
    float s = 0.f;
    #pragma unroll
    for (int u = 0; u < 16; ++u) s = fmaf(w0[u * 16 + w], xv[u], s);
    ob[(size_t)w * SP] = 0.25f * s;
  }
  #pragma unroll
  for (int w = 0; w < 16; ++w) {
    #pragma unroll
    for (int i2 = 0; i2 < 3; ++i2) {
      float s = 0.f;
      #pragma unroll
      for (int u = 0; u < 16; ++u) s = fmaf(w1[u * 16 + w], xv[16 + u * 3 + i2], s);
      ob[(size_t)(16 + w * 3 + i2) * SP] = 0.25f * s;
    }
  }
  #pragma unroll
  for (int o = 64; o < 144; ++o) ob[(size_t)o * SP] = 0.f;
}

// ---------------- direct conv, register-tiled, kw via global->regs ----------------
// block: 256 threads = 16 o-threads (9 o each) x 16 p-threads (5 z each)
// tile: 144 out-ch x (2 y x 40 z); grid = b(2) * X(40) * Ytile(20) = 1600
#define IC 8
__global__ __launch_bounds__(256, 4)
void conv_kernel(const float* __restrict__ x,
                 const float* __restrict__ kw,
                 float* __restrict__ out) {
  __shared__ float x_lds[IC][6][44];   // 6.6 KB

  int tid = threadIdx.x;
  int bid = blockIdx.x;
  int tileY = bid % 20;
  int X     = (bid / 20) % SDIM;
  int b     = bid / 800;
  int Y0 = tileY * 2;

  int p_thr = tid & 15, o_thr = tid >> 4;
  int y_loc = p_thr >> 3;          // 0..1
  int z0    = (p_thr & 7) * 5;     // 0,5,...,35
  int o_base = o_thr * 9;

  float acc[9][5];
  #pragma unroll
  for (int a = 0; a < 9; ++a)
    #pragma unroll
    for (int jj = 0; jj < 5; ++jj) acc[a][jj] = 0.f;

  const float* xb = x + (size_t)b * CIN * SP;

  #pragma unroll 1
  for (int ic = 0; ic < CIN / IC; ++ic) {
    #pragma unroll 1
    for (int dx = 0; dx < 5; ++dx) {
      int xs = X + dx - 2;
      if (xs < 0 || xs >= SDIM) continue;   // uniform across block
      __syncthreads();                       // protect x_lds from prior readers
      for (int idx = tid; idx < IC * 6 * 44; idx += 256) {
        int i   = idx / (6 * 44);
        int rem = idx % (6 * 44);
        int yy  = rem / 44, zz = rem % 44;
        int gy = Y0 + yy - 2, gz = zz - 2;
        float v = 0.f;
        if (gy >= 0 && gy < SDIM && gz >= 0 && gz < SDIM)
          v = xb[((size_t)(ic * IC + i) * SDIM + xs) * 1600 + gy * SDIM + gz];
        x_lds[i][yy][zz] = v;
      }
      __syncthreads();
      #pragma unroll 1
      for (int dy = 0; dy < 5; ++dy) {
        // kw index = (tap*CIN + ic*IC + i)*COUT + o,  tap=(dx*5+dy)*5+dz
        const float* kbase = kw
          + ((size_t)((dx * 5 + dy) * 5) * CIN + (size_t)ic * IC) * COUT + o_base;
        #pragma unroll 1
        for (int i = 0; i < IC; ++i) {
          float xr[9];
          #pragma unroll
          for (int t = 0; t < 9; ++t) xr[t] = x_lds[i][y_loc + dy][z0 + t];
          #pragma unroll
          for (int dz = 0; dz < 5; ++dz) {
            const float* kp = kbase + ((size_t)dz * CIN + i) * COUT;
            float kv[9];
            #pragma unroll
            for (int q = 0; q < 9; ++q) kv[q] = kp[q];
            #pragma unroll
            for (int oo = 0; oo < 9; ++oo)
              #pragma unroll
              for (int j = 0; j < 5; ++j)
                acc[oo][j] = fmaf(kv[oo], xr[dz + j], acc[oo][j]);
          }
        }
      }
    }
  }

  float* ob = out + (size_t)b * COUT * SP + (size_t)X * 1600;
  #pragma unroll
  for (int oo = 0; oo < 9; ++oo) {
    int o = o_base + oo;
    #pragma unroll
    for (int j = 0; j < 5; ++j) {
      size_t idx = (size_t)o * SP + (size_t)(Y0 + y_loc) * SDIM + z0 + j;
      ob[idx] += 0.1f * acc[oo][j];
    }
  }
}

// ---------------- launcher ----------------
extern "C" void kernel_launch(void* const* d_in, const int* in_sizes, int n_in,
                              void* d_out, int out_size, void* d_ws, size_t ws_size,
                              hipStream_t stream) {
  const float* x     = (const float*)d_in[0];
  const float* w_sc0 = (const float*)d_in[1];
  const float* w_sc1 = (const float*)d_in[2];
  const float* w_tp  = (const float*)d_in[3];
  float* out = (float*)d_out;
  float* kw  = (float*)d_ws;   // 4.608 MB

  build_kw<<<(KW_ELEMS + 255) / 256, 256, 0, stream>>>(w_tp, kw);
  sc_kernel<<<(2 * SP + 255) / 256, 256, 0, stream>>>(x, w_sc0, w_sc1, out);
  conv_kernel<<<2 * SDIM * 20, 256, 0, stream>>>(x, kw, out);
}

// Round 3
// 1300.029 us; speedup vs baseline: 3.7188x; 3.4563x over previous
//
#include <hip/hip_runtime.h>
#include <math.h>

#define MUL    16
#define CIN    64
#define COUT   144
#define SDIM   40
#define SP     (SDIM*SDIM*SDIM)      // 64000
#define NTAP   125
#define KW_ELEMS (NTAP*CIN*COUT)     // 1,152,000

// padded plane: 44*44 = 1936 per (b,c,x); channel stride:
#define PPLANE 1936
#define CH_STRIDE (40*1936)          // 77440
#define XP_U32   (2*64*40*1936)      // 9,912,320 u32
#define KWB_SHORTS (NTAP*2*9*64*8)   // 1,152,000 ushort each (hi / lo)

#define NBLK 176
#define WIN  356                      // 176 + 4*44 + 4

// ---------------- constants ----------------
#define SQ3    1.7320508075688772
#define SQ5    2.23606797749979
#define PW0    0.17677669529663687
#define PW1    0.25
#define PW2    0.3952847075210474
#define PW0_D3 0.10206207261596575
#define PW1_D3 0.14433756729740643
#define PW2_D5 0.17677669529663687
#define C_S    0.3651483716701107
#define C_H    0.31622776601683794

__device__ __constant__ double dC112[3][3][5] = {
  { {0.0, 0.0, -0.5*C_S, 0.0, -C_H},
    {0.0, C_H, 0.0,      0.0, 0.0 },
    {C_H, 0.0, 0.0,      0.0, 0.0 } },
  { {0.0, C_H, 0.0, 0.0, 0.0},
    {0.0, 0.0, C_S, 0.0, 0.0},
    {0.0, 0.0, 0.0, C_H, 0.0} },
  { {C_H, 0.0, 0.0, 0.0, 0.0},
    {0.0, 0.0, 0.0, C_H, 0.0},
    {0.0, 0.0, -0.5*C_S, 0.0, C_H} }
};

typedef __attribute__((ext_vector_type(4))) float f32x4;
typedef __attribute__((ext_vector_type(8))) short short8;
typedef __attribute__((ext_vector_type(8))) __bf16 bf16x8;

static __device__ __forceinline__ unsigned short f2bf(float f) {
  unsigned int u = __float_as_uint(f);
  unsigned int r = (u + 0x7fffu + ((u >> 16) & 1u)) >> 16;
  return (unsigned short)r;
}
static __device__ __forceinline__ float bf2f(unsigned short h) {
  return __uint_as_float(((unsigned int)h) << 16);
}
static __device__ __forceinline__ bf16x8 as_bf(short8 v) {
  union { short8 s; bf16x8 b; } u; u.s = v; return u.b;
}

// ---------------- shared weight-value function ----------------
static __device__ double kw_value(int tap, int i, int o, const float* __restrict__ w_tp) {
  int kz = tap % 5, ky = (tap / 5) % 5, kx = tap / 25;
  double lx = -1.0 + 0.5 * kx, ly = -1.0 + 0.5 * ky, lz = -1.0 + 0.5 * kz;
  double d = sqrt(lx*lx + ly*ly + lz*lz);
  double emb[5];
  #pragma unroll
  for (int t = 0; t < 5; ++t) {
    double diff = (d - (t + 1) / 6.0) * 6.0;
    double a = diff + 1.0, bb = 1.0 - diff;
    double sa = (a  > 0.0) ? exp(-1.0 / a)  : 0.0;
    double sb = (bb > 0.0) ? exp(-1.0 / bb) : 0.0;
    emb[t] = 1.14136 * exp(2.0) * sa * sb;
  }
  double inv = 1.0 / fmax(d, 1e-12);
  double ux = lx * inv, uy = ly * inv, uz = lz * inv;
  double sh1[3] = { SQ3 * ux, SQ3 * uy, SQ3 * uz };
  double sh2[5] = { SQ5 * SQ3 * ux * uz,
                    SQ5 * SQ3 * ux * uy,
                    SQ5 * (uy*uy - 0.5*(ux*ux + uz*uz)),
                    SQ5 * SQ3 * uy * uz,
                    SQ5 * 0.5 * SQ3 * (uz*uz - ux*ux) };

  #define WVAL(n, u, w) ({                                              \
      int base_ = (n)*256 + (u)*16 + (w);                               \
      double a_ = 0.0;                                                  \
      _Pragma("unroll")                                                 \
      for (int t_ = 0; t_ < 5; ++t_)                                    \
        a_ += emb[t_] * (double)w_tp[t_*1792 + base_];                  \
      (a_ * 0.08944271909999159); })

  double val;
  if (i < MUL) {
    int u = i;
    if (o < MUL) {
      val = PW0 * WVAL(0, u, o);
    } else if (o < 4 * MUL) {
      int w = (o - 16) / 3, k = (o - 16) % 3;
      val = PW1_D3 * sh1[k] * WVAL(1, u, w);
    } else {
      int w = (o - 64) / 5, k = (o - 64) % 5;
      val = PW2_D5 * sh2[k] * WVAL(2, u, w);
    }
  } else {
    int u = (i - 16) / 3, ii = (i - 16) % 3;
    if (o < MUL) {
      val = PW0_D3 * sh1[ii] * WVAL(4, u, o);
    } else if (o < 4 * MUL) {
      int w = (o - 16) / 3, k = (o - 16) % 3;
      double v = 0.0;
      if (ii == k) v += PW1_D3 * WVAL(3, u, w);
      double cs = 0.0;
      #pragma unroll
      for (int j = 0; j < 5; ++j) cs += dC112[ii][k][j] * sh2[j];
      v += PW1 * cs * WVAL(6, u, w);
      val = v;
    } else {
      int w = (o - 64) / 5, k = (o - 64) % 5;
      double cs = 0.0;
      #pragma unroll
      for (int j = 0; j < 3; ++j) cs += dC112[ii][j][k] * sh1[j];
      val = PW2 * cs * WVAL(5, u, w);
    }
  }
  return val;
}

// ---------------- fp32 kernel-weight builder (fallback) ----------------
__global__ void build_kw(const float* __restrict__ w_tp, float* __restrict__ kw) {
  int gid = blockIdx.x * 256 + threadIdx.x;
  if (gid >= KW_ELEMS) return;
  int o   = gid % COUT;
  int i   = (gid / COUT) % CIN;
  int tap = gid / (COUT * CIN);
  kw[gid] = (float)kw_value(tap, i, o, w_tp);
}

// ---------------- MFMA-fragment weight builder ----------------
// kwbh/kwbl[(((tap*2+ich)*9+mt)*64+lane)*8 + j], A[m=o_local][k=8*(lane>>4)+j]
__global__ void build_kwb(const float* __restrict__ w_tp,
                          unsigned short* __restrict__ kwbh,
                          unsigned short* __restrict__ kwbl) {
  int gid = blockIdx.x * 256 + threadIdx.x;
  if (gid >= NTAP * 2 * 9 * 64) return;
  int lane = gid & 63;
  int t1 = gid >> 6;
  int mt = t1 % 9;
  int t2 = t1 / 9;
  int ich = t2 & 1;
  int tap = t2 >> 1;
  int o = mt * 16 + (lane & 15);
  unsigned short h8[8], l8[8];
  #pragma unroll
  for (int j = 0; j < 8; ++j) {
    int i = ich * 32 + 8 * (lane >> 4) + j;
    float v = (float)kw_value(tap, i, o, w_tp);
    unsigned short h = f2bf(v);
    h8[j] = h;
    l8[j] = f2bf(v - bf2f(h));
  }
  #pragma unroll
  for (int j = 0; j < 8; ++j) {
    kwbh[(size_t)gid * 8 + j] = h8[j];
    kwbl[(size_t)gid * 8 + j] = l8[j];
  }
}

// ---------------- x pack: fp32 -> padded hi/lo-bf16 u32 planes ----------------
__global__ void xp_pack(const float* __restrict__ x, unsigned int* __restrict__ xp) {
  int idx = blockIdx.x * 256 + threadIdx.x;
  if (idx >= XP_U32) return;
  int qz = idx % 44;
  int t = idx / 44;
  int qy = t % 44; t /= 44;
  int xx = t % 40; t /= 40;
  int c = t % 64;
  int b = t / 64;
  int y = qy - 2, z = qz - 2;
  float v = 0.f;
  if ((unsigned)y < 40u && (unsigned)z < 40u)
    v = x[(((size_t)(b * 64 + c) * 40 + xx) * 40 + y) * 40 + z];
  unsigned short h = f2bf(v);
  unsigned short l = f2bf(v - bf2f(h));
  xp[idx] = (((unsigned int)h) << 16) | l;
}

// ---------------- self-connection ----------------
__global__ void sc_kernel(const float* __restrict__ x,
                          const float* __restrict__ w0,
                          const float* __restrict__ w1,
                          float* __restrict__ out) {
  int gid = blockIdx.x * 256 + threadIdx.x;
  if (gid >= 2 * SP) return;
  int b = gid / SP, p = gid % SP;
  const float* xb = x + (size_t)b * CIN * SP + p;
  float xv[64];
  #pragma unroll
  for (int c = 0; c < 64; ++c) xv[c] = xb[(size_t)c * SP];
  float* ob = out + (size_t)b * COUT * SP + p;
  #pragma unroll
  for (int w = 0; w < 16; ++w) {
    float s = 0.f;
    #pragma unroll
    for (int u = 0; u < 16; ++u) s = fmaf(w0[u * 16 + w], xv[u], s);
    ob[(size_t)w * SP] = 0.25f * s;
  }
  #pragma unroll
  for (int w = 0; w < 16; ++w) {
    #pragma unroll
    for (int i2 = 0; i2 < 3; ++i2) {
      float s = 0.f;
      #pragma unroll
      for (int u = 0; u < 16; ++u) s = fmaf(w1[u * 16 + w], xv[16 + u * 3 + i2], s);
      ob[(size_t)(16 + w * 3 + i2) * SP] = 0.25f * s;
    }
  }
  #pragma unroll
  for (int o = 64; o < 144; ++o) ob[(size_t)o * SP] = 0.f;
}

// ---------------- MFMA conv ----------------
// block = 4 waves; waves 0-2: N-tiles {3w..3w+2}, wave 3: {9,10,(dup 10)}
// grid = b(2) * X(40) * chunk(10); p0 = chunk*176; q = p_out + dy*44 + dz
__global__ __launch_bounds__(256, 2)
void conv_mfma(const unsigned int* __restrict__ xp,
               const unsigned short* __restrict__ kwbh,
               const unsigned short* __restrict__ kwbl,
               float* __restrict__ out) {
  __shared__ unsigned int x_lds[WIN][32];   // 45.6 KB, col-XOR-swizzled

  int tid = threadIdx.x;
  int bid = blockIdx.x;
  int chunk = bid % 10;
  int X = (bid / 10) % 40;
  int b = bid / 400;
  int p0 = chunk * NBLK;
  int wid = tid >> 6, lane = tid & 63;
  int l15 = lane & 15, g = lane >> 4;

  f32x4 acc[9][3];
  #pragma unroll
  for (int mt = 0; mt < 9; ++mt)
    #pragma unroll
    for (int nt = 0; nt < 3; ++nt)
      acc[mt][nt] = (f32x4)0.f;

  // this wave's three B-row bases (tile 11 clamped to 10 -> phantom dup)
  int tbase[3];
  #pragma unroll
  for (int nt = 0; nt < 3; ++nt) {
    int tile = wid * 3 + nt;
    if (tile > 10) tile = 10;
    tbase[nt] = tile * 16 + l15;
  }

  #pragma unroll 1
  for (int dx = 0; dx < 5; ++dx) {
    int xs = X + dx - 2;
    if (xs < 0 || xs >= 40) continue;       // uniform
    const unsigned int* xpl = xp + ((size_t)(b * 64) * 40 + xs) * PPLANE;
    #pragma unroll 1
    for (int ich = 0; ich < 2; ++ich) {
      __syncthreads();                       // protect x_lds from prior readers
      {
        int cl = tid & 3;
        int qb = tid >> 2;
        const unsigned int* src = xpl + (size_t)(ich * 32) * CH_STRIDE + p0;
        #pragma unroll
        for (int cc = 0; cc < 8; ++cc) {
          int ch = cl + cc * 4;
          const unsigned int* s2 = src + (size_t)ch * CH_STRIDE;
          #pragma unroll
          for (int qq = 0; qq < 6; ++qq) {
            int q = qb + (qq << 6);
            if (q < WIN) {
              unsigned int v = (p0 + q < PPLANE) ? s2[q] : 0u;
              x_lds[q][ch ^ ((q & 7) << 2)] = v;
            }
          }
        }
      }
      __syncthreads();
      #pragma unroll 1
      for (int dy = 0; dy < 5; ++dy) {
        #pragma unroll 1
        for (int dz = 0; dz < 5; ++dz) {
          int tap = (dx * 5 + dy) * 5 + dz;
          int shift = dy * 44 + dz;
          // ---- B fragments (hi/lo) from swizzled LDS ----
          short8 bh[3], bl[3];
          #pragma unroll
          for (int nt = 0; nt < 3; ++nt) {
            int q = tbase[nt] + shift;
            const unsigned int* row = &x_lds[q][0];
            int s = (q & 7) << 2;
            const uint4 r0 = *(const uint4*)(row + ((8 * g) ^ s));
            const uint4 r1 = *(const uint4*)(row + ((8 * g + 4) ^ s));
            unsigned int vv[8] = {r0.x, r0.y, r0.z, r0.w, r1.x, r1.y, r1.z, r1.w};
            short8 h, l;
            #pragma unroll
            for (int j = 0; j < 8; ++j) {
              h[j] = (short)(vv[j] >> 16);
              l[j] = (short)(vv[j] & 0xffffu);
            }
            bh[nt] = h; bl[nt] = l;
          }
          // ---- A fragments from global (L1/L2-hot) + MFMA ----
          const short8* ah_p = (const short8*)kwbh + ((size_t)(tap * 2 + ich) * 9) * 64 + lane;
          const short8* al_p = (const short8*)kwbl + ((size_t)(tap * 2 + ich) * 9) * 64 + lane;
          #pragma unroll
          for (int mt = 0; mt < 9; ++mt) {
            short8 ah = ah_p[mt * 64];
            short8 al = al_p[mt * 64];
            #pragma unroll
            for (int nt = 0; nt < 3; ++nt) {
              acc[mt][nt] = __builtin_amdgcn_mfma_f32_16x16x32_bf16(as_bf(ah), as_bf(bh[nt]), acc[mt][nt], 0, 0, 0);
              acc[mt][nt] = __builtin_amdgcn_mfma_f32_16x16x32_bf16(as_bf(ah), as_bf(bl[nt]), acc[mt][nt], 0, 0, 0);
              acc[mt][nt] = __builtin_amdgcn_mfma_f32_16x16x32_bf16(as_bf(al), as_bf(bh[nt]), acc[mt][nt], 0, 0, 0);
            }
          }
        }
      }
    }
  }

  // ---- epilogue: out += 0.1*acc (sc already in out) ----
  float* ob = out + (size_t)b * COUT * SP + (size_t)X * 1600;
  #pragma unroll
  for (int mt = 0; mt < 9; ++mt) {
    #pragma unroll
    for (int nt = 0; nt < 3; ++nt) {
      if (wid == 3 && nt == 2) continue;     // phantom tile
      int p = p0 + (wid * 3 + nt) * 16 + l15;
      int y = p / 44, z = p - y * 44;
      if (z < 40) {
        #pragma unroll
        for (int r = 0; r < 4; ++r) {
          int o = mt * 16 + g * 4 + r;
          float* dst = ob + (size_t)o * SP + y * 40 + z;
          *dst += 0.1f * acc[mt][nt][r];
        }
      }
    }
  }
}

// ---------------- fp32 fallback conv (R2) ----------------
#define IC 8
__global__ __launch_bounds__(256, 4)
void conv_kernel(const float* __restrict__ x,
                 const float* __restrict__ kw,
                 float* __restrict__ out) {
  __shared__ float x_lds[IC][6][44];

  int tid = threadIdx.x;
  int bid = blockIdx.x;
  int tileY = bid % 20;
  int X     = (bid / 20) % SDIM;
  int b     = bid / 800;
  int Y0 = tileY * 2;

  int p_thr = tid & 15, o_thr = tid >> 4;
  int y_loc = p_thr >> 3;
  int z0    = (p_thr & 7) * 5;
  int o_base = o_thr * 9;

  float acc[9][5];
  #pragma unroll
  for (int a = 0; a < 9; ++a)
    #pragma unroll
    for (int jj = 0; jj < 5; ++jj) acc[a][jj] = 0.f;

  const float* xb = x + (size_t)b * CIN * SP;

  #pragma unroll 1
  for (int ic = 0; ic < CIN / IC; ++ic) {
    #pragma unroll 1
    for (int dx = 0; dx < 5; ++dx) {
      int xs = X + dx - 2;
      if (xs < 0 || xs >= SDIM) continue;
      __syncthreads();
      for (int idx = tid; idx < IC * 6 * 44; idx += 256) {
        int i   = idx / (6 * 44);
        int rem = idx % (6 * 44);
        int yy  = rem / 44, zz = rem % 44;
        int gy = Y0 + yy - 2, gz = zz - 2;
        float v = 0.f;
        if (gy >= 0 && gy < SDIM && gz >= 0 && gz < SDIM)
          v = xb[((size_t)(ic * IC + i) * SDIM + xs) * 1600 + gy * SDIM + gz];
        x_lds[i][yy][zz] = v;
      }
      __syncthreads();
      #pragma unroll 1
      for (int dy = 0; dy < 5; ++dy) {
        const float* kbase = kw
          + ((size_t)((dx * 5 + dy) * 5) * CIN + (size_t)ic * IC) * COUT + o_base;
        #pragma unroll 1
        for (int i = 0; i < IC; ++i) {
          float xr[9];
          #pragma unroll
          for (int t = 0; t < 9; ++t) xr[t] = x_lds[i][y_loc + dy][z0 + t];
          #pragma unroll
          for (int dz = 0; dz < 5; ++dz) {
            const float* kp = kbase + ((size_t)dz * CIN + i) * COUT;
            float kv[9];
            #pragma unroll
            for (int q = 0; q < 9; ++q) kv[q] = kp[q];
            #pragma unroll
            for (int oo = 0; oo < 9; ++oo)
              #pragma unroll
              for (int j = 0; j < 5; ++j)
                acc[oo][j] = fmaf(kv[oo], xr[dz + j], acc[oo][j]);
          }
        }
      }
    }
  }

  float* ob = out + (size_t)b * COUT * SP + (size_t)X * 1600;
  #pragma unroll
  for (int oo = 0; oo < 9; ++oo) {
    int o = o_base + oo;
    #pragma unroll
    for (int j = 0; j < 5; ++j) {
      size_t idx = (size_t)o * SP + (size_t)(Y0 + y_loc) * SDIM + z0 + j;
      ob[idx] += 0.1f * acc[oo][j];
    }
  }
}

// ---------------- launcher ----------------
extern "C" void kernel_launch(void* const* d_in, const int* in_sizes, int n_in,
                              void* d_out, int out_size, void* d_ws, size_t ws_size,
                              hipStream_t stream) {
  const float* x     = (const float*)d_in[0];
  const float* w_sc0 = (const float*)d_in[1];
  const float* w_sc1 = (const float*)d_in[2];
  const float* w_tp  = (const float*)d_in[3];
  float* out = (float*)d_out;

  size_t xp_bytes  = (size_t)XP_U32 * 4;           // 39,649,280
  size_t kwb_bytes = (size_t)KWB_SHORTS * 2;       // 2,304,000 each
  size_t need = xp_bytes + 2 * kwb_bytes;

  if (ws_size >= need) {
    unsigned int*  xp   = (unsigned int*)d_ws;
    unsigned short* kwbh = (unsigned short*)((char*)d_ws + xp_bytes);
    unsigned short* kwbl = (unsigned short*)((char*)d_ws + xp_bytes + kwb_bytes);

    xp_pack<<<(XP_U32 + 255) / 256, 256, 0, stream>>>(x, xp);
    build_kwb<<<(NTAP * 2 * 9 * 64 + 255) / 256, 256, 0, stream>>>(w_tp, kwbh, kwbl);
    sc_kernel<<<(2 * SP + 255) / 256, 256, 0, stream>>>(x, w_sc0, w_sc1, out);
    conv_mfma<<<2 * 40 * 10, 256, 0, stream>>>(xp, kwbh, kwbl, out);
  } else {
    float* kw = (float*)d_ws;
    build_kw<<<(KW_ELEMS + 255) / 256, 256, 0, stream>>>(w_tp, kw);
    sc_kernel<<<(2 * SP + 255) / 256, 256, 0, stream>>>(x, w_sc0, w_sc1, out);
    conv_kernel<<<2 * SDIM * 20, 256, 0, stream>>>(x, kw, out);
  }
}